// Round 4
// baseline (535.445 us; speedup 1.0000x reference)
//
#include <hip/hip_runtime.h>
#include <stdint.h>

// Problem constants (from reference):
//   VOC_SIZE = 1,000,000, EMBED_DIM = 64, N_UPD = 262,144, B*L = 819,200
// Inputs:
//   d_in[0]: kernel      float32 [1,000,000 * 64]   (mutated in place; harness
//                                                    restores unconditionally)
//   d_in[1]: indices     int32   [262,144]
//   d_in[2]: emb_update  float32 [262,144 * 64]
//   d_in[3]: qs          int32   [819,200]
// Output: float32 [819,200 * 64]
//
// Round-3 lesson: dur_us responds 1:1 to kernel time; fills/restores are a
// fixed ~300us. Attack the kernels:
//   - Dead-update elimination: out depends only on rows named in qs (~56% of
//     vocab). Build a query bitmap (125 KB, L2-resident), and skip the entire
//     scatter wave (upd load + atomic RMW) for unqueried rows (~44%).
//     Bit-identical output: skipped updates are never read by the gather.
//   - Gather at 32 B/lane: two independent dwordx4 loads per thread doubles
//     MLP for the latency-bound random row reads, halves wave count.

#define EMBED_DIM 64
#define VOC 1000000
#define BITWORDS ((VOC + 31) / 32)   // 31,250 u32 = 125 KB

typedef float floatx4 __attribute__((ext_vector_type(4)));

__global__ __launch_bounds__(256) void zero_bitmap_kernel(
        unsigned* __restrict__ bm, int n) {
    int t = blockIdx.x * blockDim.x + threadIdx.x;
    if (t < n) bm[t] = 0u;
}

__global__ __launch_bounds__(256) void build_bitmap_kernel(
        const int* __restrict__ qs, unsigned* __restrict__ bm, int n_q) {
    int t = blockIdx.x * blockDim.x + threadIdx.x;
    if (t >= n_q) return;
    int q = qs[t];
    atomicOr(&bm[q >> 5], 1u << (q & 31));
}

// One thread per update element; 64 consecutive threads = one wave = one
// update row (row index is wave-uniform). If the row is never queried, the
// whole wave exits before touching upd or the table. bm==nullptr disables
// the filter (no-workspace fallback).
__global__ __launch_bounds__(256) void scatter_add_kernel(
        float* __restrict__ table,
        const int* __restrict__ indices,
        const float* __restrict__ upd,
        const unsigned* __restrict__ bm,
        int total /* n_upd * 64 */) {
    int tid = blockIdx.x * blockDim.x + threadIdx.x;
    if (tid >= total) return;
    int i = tid >> 6;   // update row (wave-uniform)
    int d = tid & 63;   // column
    int row = indices[i];
    if (bm && !((bm[row >> 5] >> (row & 31)) & 1u)) return;  // never queried
    float v = __builtin_nontemporal_load(&upd[tid]);
#if defined(__HIP_DEVICE_COMPILE__)
    unsafeAtomicAdd(&table[(size_t)row * EMBED_DIM + d], v);
#else
    atomicAdd(&table[(size_t)row * EMBED_DIM + d], v);
#endif
}

// 8 threads per query row, 32 B (two float4) per thread: two independent
// global loads in flight per thread for the latency-bound random row fetch.
__global__ __launch_bounds__(256) void gather_kernel(
        const floatx4* __restrict__ table,
        const int* __restrict__ qs,
        floatx4* __restrict__ out,
        int total /* n_q * 8 */) {
    int tid = blockIdx.x * blockDim.x + threadIdx.x;
    if (tid >= total) return;
    int r = tid >> 3;   // query index
    int c = tid & 7;    // 32 B chunk within the row
    int q = qs[r];
    size_t base = (size_t)q * 16 + (size_t)c * 2;
    floatx4 a = table[base];
    floatx4 b = table[base + 1];
    size_t o = (size_t)tid * 2;
    __builtin_nontemporal_store(a, &out[o]);
    __builtin_nontemporal_store(b, &out[o + 1]);
}

extern "C" void kernel_launch(void* const* d_in, const int* in_sizes, int n_in,
                              void* d_out, int out_size, void* d_ws, size_t ws_size,
                              hipStream_t stream) {
    float* table = (float*)d_in[0];                    // mutated in place
    const int* indices = (const int*)d_in[1];
    const float* upd = (const float*)d_in[2];
    const int* qs = (const int*)d_in[3];
    float* out = (float*)d_out;

    const int n_upd = in_sizes[1];                     // 262,144
    const int n_q = in_sizes[3];                       // 819,200

    const int scatter_total = n_upd * EMBED_DIM;       // 16,777,216
    const int gather_total = n_q * (EMBED_DIM / 8);    // 6,553,600
    const int block = 256;

    unsigned* bm = nullptr;
    if (ws_size >= BITWORDS * sizeof(unsigned)) {
        bm = (unsigned*)d_ws;                          // 125 KB in workspace
        zero_bitmap_kernel<<<(BITWORDS + block - 1) / block, block, 0, stream>>>(
            bm, BITWORDS);
        build_bitmap_kernel<<<(n_q + block - 1) / block, block, 0, stream>>>(
            qs, bm, n_q);
    }

    scatter_add_kernel<<<(scatter_total + block - 1) / block, block, 0, stream>>>(
        table, indices, upd, bm, scatter_total);

    gather_kernel<<<(gather_total + block - 1) / block, block, 0, stream>>>(
        (const floatx4*)table, qs, (floatx4*)out, gather_total);
}